// Round 2
// baseline (555.825 us; speedup 1.0000x reference)
//
#include <hip/hip_runtime.h>

typedef __attribute__((ext_vector_type(8))) short bf16x8;
typedef __attribute__((ext_vector_type(16))) float f32x16;

union FragU { bf16x8 v; unsigned int u[4]; };
struct Wptrs { const float* p[16]; };

__device__ __forceinline__ unsigned int bfb(float f) {
  unsigned int u = __builtin_bit_cast(unsigned int, f);
  return (u + 0x7fffu + ((u >> 16) & 1u)) >> 16;   // RNE f32 -> bf16 bits
}
__device__ __forceinline__ unsigned int cvtpk(float lo, float hi) {
  unsigned int d;
  asm("v_cvt_pk_bf16_f32 %0, %1, %2" : "=v"(d) : "v"(lo), "v"(hi));
  return d;
}
__device__ __forceinline__ float silu_f(float x) {
  float e = __builtin_amdgcn_exp2f(-1.4426950408889634f * x);
  return x * __builtin_amdgcn_rcpf(1.0f + e);
}
__device__ __forceinline__ f32x16 zero16() {
  f32x16 z;
  #pragma unroll
  for (int i = 0; i < 16; ++i) z[i] = 0.0f;
  return z;
}

// A fragment (32x32x16 bf16): lane row = l31, k = h*16 + hi*8 .. +8
__device__ __forceinline__ bf16x8 ldA(const unsigned short* __restrict__ wsb, int tile, int l31, int hi, int h) {
  return *(const bf16x8*)(wsb + ((tile * 32 + l31) << 5) + h * 16 + hi * 8);
}

// C layout (32x32x16): col p = lane&31, row j = (reg&3)+8*(reg>>2)+4*hi.
// Next-layer B frag via 4x v_permlane32_swap_b32:
//   swap(a,b): a[l>=32] <- b[l-32];  b[l<32] <- a[l+32]
// giving (f.u[lo], f.u[hi]) pairs directly (same network as the verified
// cndmask+shfl version of round 1).
__device__ __forceinline__ void transition(const f32x16& acc, bf16x8& b0, bf16x8& b1) {
  unsigned int P[8];
  #pragma unroll
  for (int t = 0; t < 8; ++t)
    P[t] = cvtpk(silu_f(acc[2*t]), silu_f(acc[2*t+1]));
  asm volatile("v_permlane32_swap_b32 %0, %1" : "+v"(P[0]), "+v"(P[2]));
  asm volatile("v_permlane32_swap_b32 %0, %1" : "+v"(P[1]), "+v"(P[3]));
  asm volatile("v_permlane32_swap_b32 %0, %1" : "+v"(P[4]), "+v"(P[6]));
  asm volatile("v_permlane32_swap_b32 %0, %1" : "+v"(P[5]), "+v"(P[7]));
  FragU f0, f1;
  f0.u[0] = P[0]; f0.u[1] = P[1]; f0.u[2] = P[2]; f0.u[3] = P[3];
  f1.u[0] = P[4]; f1.u[1] = P[5]; f1.u[2] = P[6]; f1.u[3] = P[7];
  b0 = f0.v; b1 = f1.v;
}

template<int NL, int OFF, int TB>
__device__ __forceinline__ void doPhase(const unsigned short* __restrict__ wsb,
    const float* __restrict__ rp, float* __restrict__ op,
    int s, int hi, int l31, bool act)
{
  // layer-1 B frags straight from global: lane reads contiguous floats of its row
  FragU bx0, bx1;
  {
    int kl = hi * 8;
    float4 q0 = make_float4(0.f,0.f,0.f,0.f), q1 = q0;
    if (kl + 4 <= NL) q0 = *(const float4*)(rp + OFF + kl);
    if (kl + 8 <= NL) q1 = *(const float4*)(rp + OFF + kl + 4);
    bx0.u[0] = cvtpk(q0.x, q0.y); bx0.u[1] = cvtpk(q0.z, q0.w);
    bx0.u[2] = cvtpk(q1.x, q1.y); bx0.u[3] = cvtpk(q1.z, q1.w);
    if (NL > 16) {
      int k2 = 16 + hi * 8;
      float4 r0 = make_float4(0.f,0.f,0.f,0.f), r1 = r0;
      if (k2 + 4 <= NL) r0 = *(const float4*)(rp + OFF + k2);
      if (k2 + 8 <= NL) r1 = *(const float4*)(rp + OFF + k2 + 4);
      bx1.u[0] = cvtpk(r0.x, r0.y); bx1.u[1] = cvtpk(r0.z, r0.w);
      bx1.u[2] = cvtpk(r1.x, r1.y); bx1.u[3] = cvtpk(r1.z, r1.w);
    }
  }

  f32x16 acc = zero16();
  acc = __builtin_amdgcn_mfma_f32_32x32x16_bf16(ldA(wsb, TB + s, l31, hi, 0), bx0.v, acc, 0, 0, 0);
  if (NL > 16)
    acc = __builtin_amdgcn_mfma_f32_32x32x16_bf16(ldA(wsb, TB + s, l31, hi, 1), bx1.v, acc, 0, 0, 0);
  bf16x8 b0, b1;
  transition(acc, b0, b1);
  acc = zero16();
  acc = __builtin_amdgcn_mfma_f32_32x32x16_bf16(ldA(wsb, TB + 4 + s, l31, hi, 0), b0, acc, 0, 0, 0);
  acc = __builtin_amdgcn_mfma_f32_32x32x16_bf16(ldA(wsb, TB + 4 + s, l31, hi, 1), b1, acc, 0, 0, 0);
  transition(acc, b0, b1);
  acc = zero16();
  acc = __builtin_amdgcn_mfma_f32_32x32x16_bf16(ldA(wsb, TB + 8 + s, l31, hi, 0), b0, acc, 0, 0, 0);
  acc = __builtin_amdgcn_mfma_f32_32x32x16_bf16(ldA(wsb, TB + 8 + s, l31, hi, 1), b1, acc, 0, 0, 0);
  transition(acc, b0, b1);
  acc = zero16();
  acc = __builtin_amdgcn_mfma_f32_32x32x16_bf16(ldA(wsb, TB + 12 + s, l31, hi, 0), b0, acc, 0, 0, 0);
  acc = __builtin_amdgcn_mfma_f32_32x32x16_bf16(ldA(wsb, TB + 12 + s, l31, hi, 1), b1, acc, 0, 0, 0);

  // store: reg quad t -> jo = 8t + 4hi + 0..3 (contiguous, 16B aligned)
  if (act) {
    #pragma unroll
    for (int t = 0; t < 4; ++t) {
      if (8*t + 4*hi + 4 <= NL) {
        float4 v = make_float4(acc[4*t], acc[4*t+1], acc[4*t+2], acc[4*t+3]);
        *(float4*)(op + OFF + 8*t + 4*hi) = v;
      }
    }
  }
}

// weights -> bf16 fragment-ready layout in d_ws:
// ws[l][tile 0..15][j 0..31][k 0..31], tile = layer*4 + species, zeros in K/J pads
__global__ void convert_weights_kernel(Wptrs wp, unsigned short* __restrict__ wsb) {
  int idx = blockIdx.x * 256 + threadIdx.x;          // 65536 total
  const int NLs[4] = {24, 20, 16, 12};
  int l = idx >> 14, r = idx & 16383;
  int tile = r >> 10, j = (r >> 5) & 31, k = r & 31;
  int s = tile & 3, layer = tile >> 2;
  int NL = NLs[l];
  const float* w = wp.p[l * 4 + layer];
  float v = 0.0f;
  if (layer == 0)      { if (k < NL) v = w[(s * NL + k) * 32 + j]; }
  else if (layer == 3) { if (j < NL) v = w[(s * 32 + k) * NL + j]; }
  else                 { v = w[(s * 32 + k) * 32 + j]; }
  wsb[idx] = (unsigned short)bfb(v);
}

__global__ __launch_bounds__(256, 6) void RadialBasis_51316269253437_kernel(
    const float* __restrict__ rad, const int* __restrict__ spc,
    const unsigned short* __restrict__ wsb, float* __restrict__ out, int npairs)
{
  __shared__ unsigned short s_perm[1024];
  __shared__ int s_cnt[4], s_fill[4], s_off[4], s_gpre[5];
  const int tid = threadIdx.x;
  const int base = blockIdx.x << 10;
  int vb = npairs - base; if (vb > 1024) vb = 1024;

  if (tid < 4) { s_cnt[tid] = 0; s_fill[tid] = 0; }
  __syncthreads();
  int sps[4];
  #pragma unroll
  for (int t = 0; t < 4; ++t) {
    int i = t * 256 + tid;
    int sp = -1;
    if (i < vb) sp = spc[base + i];
    sps[t] = sp;
    if (sp >= 0) atomicAdd(&s_cnt[sp], 1);
  }
  __syncthreads();
  if (tid == 0) {
    int o = 0, gp = 0;
    #pragma unroll
    for (int s4 = 0; s4 < 4; ++s4) {
      s_off[s4] = o; o += s_cnt[s4];
      s_gpre[s4] = gp; gp += (s_cnt[s4] + 31) >> 5;
    }
    s_gpre[4] = gp;
  }
  __syncthreads();
  #pragma unroll
  for (int t = 0; t < 4; ++t) {
    int sp = sps[t];
    if (sp >= 0) {
      int pos = s_off[sp] + atomicAdd(&s_fill[sp], 1);
      s_perm[pos] = (unsigned short)(t * 256 + tid);
    }
  }
  __syncthreads();

  const int lane = tid & 63, wid = tid >> 6;
  const int l31 = lane & 31, hi = lane >> 5;
  const int Gtot = s_gpre[4];
  for (int g = wid; g < Gtot; g += 4) {
    int s = (g >= s_gpre[1]) + (g >= s_gpre[2]) + (g >= s_gpre[3]);
    int gi = g - s_gpre[s];
    int goff = s_off[s] + gi * 32;
    int gcnt = s_cnt[s] - gi * 32; if (gcnt > 32) gcnt = 32;
    int li = l31 < gcnt ? l31 : gcnt - 1;
    long row = base + (int)s_perm[goff + li];
    const float* rp = rad + row * 72;
    float* op = out + row * 72;
    bool act = l31 < gcnt;
    doPhase<24,  0,  0>(wsb, rp, op, s, hi, l31, act);
    doPhase<20, 24, 16>(wsb, rp, op, s, hi, l31, act);
    doPhase<16, 44, 32>(wsb, rp, op, s, hi, l31, act);
    doPhase<12, 60, 48>(wsb, rp, op, s, hi, l31, act);
  }
}

extern "C" void kernel_launch(void* const* d_in, const int* in_sizes, int n_in,
                              void* d_out, int out_size, void* d_ws, size_t ws_size,
                              hipStream_t stream) {
  const float* rad = (const float*)d_in[0];
  const int* spc = (const int*)d_in[1];
  Wptrs wp;
  for (int i = 0; i < 16; ++i) wp.p[i] = (const float*)d_in[2 + i];
  float* out = (float*)d_out;
  unsigned short* wsb = (unsigned short*)d_ws;
  int npairs = in_sizes[0] / 72;

  convert_weights_kernel<<<dim3(256), dim3(256), 0, stream>>>(wp, wsb);
  int grid = (npairs + 1023) >> 10;
  RadialBasis_51316269253437_kernel<<<dim3(grid), dim3(256), 0, stream>>>(rad, spc, wsb, out, npairs);
}

// Round 3
// 529.625 us; speedup vs baseline: 1.0495x; 1.0495x over previous
//
#include <hip/hip_runtime.h>

typedef __attribute__((ext_vector_type(8))) short bf16x8;
typedef __attribute__((ext_vector_type(16))) float f32x16;

union FragU { bf16x8 v; unsigned int u[4]; };
struct Wptrs { const float* p[16]; };

#define ROWS 512

__device__ __forceinline__ unsigned int bfb(float f) {
  unsigned int u = __builtin_bit_cast(unsigned int, f);
  return (u + 0x7fffu + ((u >> 16) & 1u)) >> 16;   // RNE f32 -> bf16 bits
}
__device__ __forceinline__ unsigned int cvtpk(float lo, float hi) {
  unsigned int d;
  asm("v_cvt_pk_bf16_f32 %0, %1, %2" : "=v"(d) : "v"(lo), "v"(hi));
  return d;
}
__device__ __forceinline__ float bf2f(unsigned short b) {
  return __builtin_bit_cast(float, (unsigned int)b << 16);
}
__device__ __forceinline__ float silu_f(float x) {
  float e = __builtin_amdgcn_exp2f(-1.4426950408889634f * x);
  return x * __builtin_amdgcn_rcpf(1.0f + e);
}
__device__ __forceinline__ f32x16 zero16() {
  f32x16 z;
  #pragma unroll
  for (int i = 0; i < 16; ++i) z[i] = 0.0f;
  return z;
}

// A fragment (32x32x16 bf16): lane row = l31, k = h*16 + hi*8 .. +8, from global bf16 weights
__device__ __forceinline__ bf16x8 ldA(const unsigned short* __restrict__ wsb, int tile, int l31, int hi, int h) {
  return *(const bf16x8*)(wsb + ((tile * 32 + l31) << 5) + h * 16 + hi * 8);
}

// C layout (32x32x16): col p = lane&31, row j = (reg&3)+8*(reg>>2)+4*hi.
// Next-layer B frag via 4x v_permlane32_swap_b32 (verified R1/R2 network).
__device__ __forceinline__ void transition(const f32x16& acc, bf16x8& b0, bf16x8& b1) {
  unsigned int P[8];
  #pragma unroll
  for (int t = 0; t < 8; ++t)
    P[t] = cvtpk(silu_f(acc[2*t]), silu_f(acc[2*t+1]));
  asm volatile("v_permlane32_swap_b32 %0, %1" : "+v"(P[0]), "+v"(P[2]));
  asm volatile("v_permlane32_swap_b32 %0, %1" : "+v"(P[1]), "+v"(P[3]));
  asm volatile("v_permlane32_swap_b32 %0, %1" : "+v"(P[4]), "+v"(P[6]));
  asm volatile("v_permlane32_swap_b32 %0, %1" : "+v"(P[5]), "+v"(P[7]));
  FragU f0, f1;
  f0.u[0] = P[0]; f0.u[1] = P[1]; f0.u[2] = P[2]; f0.u[3] = P[3];
  f1.u[0] = P[4]; f1.u[1] = P[5]; f1.u[2] = P[6]; f1.u[3] = P[7];
  b0 = f0.v; b1 = f1.v;
}

// Per phase: zero s_in pads -> stage rad slice coalesced into s_in (permuted, bf16)
// -> MFMA groups (s_in -> s_out) -> write out coalesced from s_out.
// SI/SO strides (elems) chosen 16B/8B-aligned per row and bank-sweep-friendly.
template<int NL, int OFF, int TB, int SI, int SO>
__device__ __forceinline__ void phase(const float* __restrict__ rad, float* __restrict__ out,
    const unsigned short* __restrict__ wsb,
    unsigned short* s_in, unsigned short* s_out, const unsigned short* s_pos,
    const int* s_cnt, const int* s_off, const int* s_gpre,
    int base, int vb, int tid)
{
  constexpr int QPR = NL / 4;
  __syncthreads();                       // prev phase done with s_in/s_out
  {                                      // zero s_in (pad lanes must be 0 for MFMA K/J pads)
    int4 z = make_int4(0, 0, 0, 0);
    #pragma unroll
    for (int i = 0; i < (ROWS * SI) / (8 * 256); ++i)
      ((int4*)s_in)[i * 256 + tid] = z;
  }
  __syncthreads();
  // stage-in: coalesced global read, permuted LDS write
  for (int j = tid; j < vb * QPR; j += 256) {
    int i = j / QPR, q = j - i * QPR;
    float4 g = *(const float4*)(rad + (long)(base + i) * 72 + OFF + q * 4);
    int dst = s_pos[i];
    unsigned int u0 = cvtpk(g.x, g.y), u1 = cvtpk(g.z, g.w);
    *(uint2*)(s_in + dst * SI + q * 4) = make_uint2(u0, u1);
  }
  __syncthreads();

  // compute: species-uniform 32-row groups
  const int lane = tid & 63, wid = tid >> 6;
  const int l31 = lane & 31, hi = lane >> 5;
  const int Gtot = s_gpre[4];
  for (int g = wid; g < Gtot; g += 4) {
    int s = (g >= s_gpre[1]) + (g >= s_gpre[2]) + (g >= s_gpre[3]);
    int gi = g - s_gpre[s];
    int goff = s_off[s] + gi * 32;
    int gcnt = s_cnt[s] - gi * 32; if (gcnt > 32) gcnt = 32;
    int li = l31 < gcnt ? l31 : gcnt - 1;
    int row = goff + li;

    FragU bx0, bx1;
    bx0.v = *(const bf16x8*)(s_in + row * SI + hi * 8);
    if (NL > 16) bx1.v = *(const bf16x8*)(s_in + row * SI + 16 + hi * 8);

    f32x16 acc = zero16();
    acc = __builtin_amdgcn_mfma_f32_32x32x16_bf16(ldA(wsb, TB + s, l31, hi, 0), bx0.v, acc, 0, 0, 0);
    if (NL > 16)
      acc = __builtin_amdgcn_mfma_f32_32x32x16_bf16(ldA(wsb, TB + s, l31, hi, 1), bx1.v, acc, 0, 0, 0);
    bf16x8 b0, b1;
    transition(acc, b0, b1);
    acc = zero16();
    acc = __builtin_amdgcn_mfma_f32_32x32x16_bf16(ldA(wsb, TB + 4 + s, l31, hi, 0), b0, acc, 0, 0, 0);
    acc = __builtin_amdgcn_mfma_f32_32x32x16_bf16(ldA(wsb, TB + 4 + s, l31, hi, 1), b1, acc, 0, 0, 0);
    transition(acc, b0, b1);
    acc = zero16();
    acc = __builtin_amdgcn_mfma_f32_32x32x16_bf16(ldA(wsb, TB + 8 + s, l31, hi, 0), b0, acc, 0, 0, 0);
    acc = __builtin_amdgcn_mfma_f32_32x32x16_bf16(ldA(wsb, TB + 8 + s, l31, hi, 1), b1, acc, 0, 0, 0);
    transition(acc, b0, b1);
    acc = zero16();
    acc = __builtin_amdgcn_mfma_f32_32x32x16_bf16(ldA(wsb, TB + 12 + s, l31, hi, 0), b0, acc, 0, 0, 0);
    acc = __builtin_amdgcn_mfma_f32_32x32x16_bf16(ldA(wsb, TB + 12 + s, l31, hi, 1), b1, acc, 0, 0, 0);

    // quads: reg quad t -> jo = 8t + 4hi + 0..3; store bf16 to s_out
    if (l31 < gcnt) {
      int orow = goff + l31;
      #pragma unroll
      for (int t = 0; t < 4; ++t) {
        if (8 * t + 4 * hi + 4 <= NL) {
          unsigned int u0 = cvtpk(acc[4*t], acc[4*t+1]);
          unsigned int u1 = cvtpk(acc[4*t+2], acc[4*t+3]);
          *(uint2*)(s_out + orow * SO + 8 * t + 4 * hi) = make_uint2(u0, u1);
        }
      }
    }
  }
  __syncthreads();
  // out-stage: permuted LDS read, coalesced global write
  for (int j = tid; j < vb * QPR; j += 256) {
    int i = j / QPR, q = j - i * QPR;
    int src = s_pos[i];
    uint2 w = *(const uint2*)(s_out + src * SO + q * 4);
    float4 v = make_float4(bf2f((unsigned short)(w.x & 0xffff)),
                           bf2f((unsigned short)(w.x >> 16)),
                           bf2f((unsigned short)(w.y & 0xffff)),
                           bf2f((unsigned short)(w.y >> 16)));
    *(float4*)(out + (long)(base + i) * 72 + OFF + q * 4) = v;
  }
}

// weights -> bf16 fragment-ready layout in d_ws:
// ws[l][tile 0..15][j 0..31][k 0..31], tile = layer*4 + species, zeros in K/J pads
__global__ void convert_weights_kernel(Wptrs wp, unsigned short* __restrict__ wsb) {
  int idx = blockIdx.x * 256 + threadIdx.x;          // 65536 total
  const int NLs[4] = {24, 20, 16, 12};
  int l = idx >> 14, r = idx & 16383;
  int tile = r >> 10, j = (r >> 5) & 31, k = r & 31;
  int s = tile & 3, layer = tile >> 2;
  int NL = NLs[l];
  const float* w = wp.p[l * 4 + layer];
  float v = 0.0f;
  if (layer == 0)      { if (k < NL) v = w[(s * NL + k) * 32 + j]; }
  else if (layer == 3) { if (j < NL) v = w[(s * 32 + k) * NL + j]; }
  else                 { v = w[(s * 32 + k) * 32 + j]; }
  wsb[idx] = (unsigned short)bfb(v);
}

__global__ __launch_bounds__(256, 2) void RadialBasis_51316269253437_kernel(
    const float* __restrict__ rad, const int* __restrict__ spc,
    const unsigned short* __restrict__ wsb, float* __restrict__ out, int npairs)
{
  __shared__ unsigned short s_in[ROWS * 32];    // 32 KB
  __shared__ unsigned short s_out[ROWS * 24];   // 24 KB
  __shared__ unsigned short s_pos[ROWS];        // 1 KB
  __shared__ int s_cnt[4], s_fill[4], s_off[4], s_gpre[5];
  const int tid = threadIdx.x;
  const int base = blockIdx.x * ROWS;
  int vb = npairs - base; if (vb > ROWS) vb = ROWS;

  if (tid < 4) { s_cnt[tid] = 0; s_fill[tid] = 0; }
  __syncthreads();
  int sps[2];
  #pragma unroll
  for (int t = 0; t < 2; ++t) {
    int i = t * 256 + tid;
    int sp = -1;
    if (i < vb) sp = spc[base + i];
    sps[t] = sp;
    if (sp >= 0) atomicAdd(&s_cnt[sp], 1);
  }
  __syncthreads();
  if (tid == 0) {
    int o = 0, gp = 0;
    #pragma unroll
    for (int s4 = 0; s4 < 4; ++s4) {
      s_off[s4] = o; o += s_cnt[s4];
      s_gpre[s4] = gp; gp += (s_cnt[s4] + 31) >> 5;
    }
    s_gpre[4] = gp;
  }
  __syncthreads();
  #pragma unroll
  for (int t = 0; t < 2; ++t) {
    int sp = sps[t];
    if (sp >= 0) {
      int pos = s_off[sp] + atomicAdd(&s_fill[sp], 1);
      s_pos[t * 256 + tid] = (unsigned short)pos;
    }
  }
  // phases (each starts with its own __syncthreads)
  phase<24,  0,  0, 32, 24>(rad, out, wsb, s_in, s_out, s_pos, s_cnt, s_off, s_gpre, base, vb, tid);
  phase<20, 24, 16, 32, 20>(rad, out, wsb, s_in, s_out, s_pos, s_cnt, s_off, s_gpre, base, vb, tid);
  phase<16, 44, 32, 24, 20>(rad, out, wsb, s_in, s_out, s_pos, s_cnt, s_off, s_gpre, base, vb, tid);
  phase<12, 60, 48, 24, 20>(rad, out, wsb, s_in, s_out, s_pos, s_cnt, s_off, s_gpre, base, vb, tid);
}

extern "C" void kernel_launch(void* const* d_in, const int* in_sizes, int n_in,
                              void* d_out, int out_size, void* d_ws, size_t ws_size,
                              hipStream_t stream) {
  const float* rad = (const float*)d_in[0];
  const int* spc = (const int*)d_in[1];
  Wptrs wp;
  for (int i = 0; i < 16; ++i) wp.p[i] = (const float*)d_in[2 + i];
  float* out = (float*)d_out;
  unsigned short* wsb = (unsigned short*)d_ws;
  int npairs = in_sizes[0] / 72;

  convert_weights_kernel<<<dim3(256), dim3(256), 0, stream>>>(wp, wsb);
  int grid = (npairs + ROWS - 1) / ROWS;
  RadialBasis_51316269253437_kernel<<<dim3(grid), dim3(256), 0, stream>>>(rad, spc, wsb, out, npairs);
}

// Round 7
// 473.406 us; speedup vs baseline: 1.1741x; 1.1188x over previous
//
#include <hip/hip_runtime.h>

typedef __attribute__((ext_vector_type(8))) short bf16x8;
typedef __attribute__((ext_vector_type(16))) float f32x16;

union FragU { bf16x8 v; unsigned int u[4]; };
struct Wptrs { const float* p[16]; };

#define ROWS 256

__device__ __forceinline__ unsigned int bfb(float f) {
  unsigned int u = __builtin_bit_cast(unsigned int, f);
  return (u + 0x7fffu + ((u >> 16) & 1u)) >> 16;   // RNE f32 -> bf16 bits
}
__device__ __forceinline__ unsigned int cvtpk(float lo, float hi) {
  unsigned int d;
  asm("v_cvt_pk_bf16_f32 %0, %1, %2" : "=v"(d) : "v"(lo), "v"(hi));
  return d;
}
__device__ __forceinline__ float bf2f(unsigned short b) {
  return __builtin_bit_cast(float, (unsigned int)b << 16);
}
__device__ __forceinline__ float silu_f(float x) {
  float e = __builtin_amdgcn_exp2f(-1.4426950408889634f * x);
  return x * __builtin_amdgcn_rcpf(1.0f + e);
}
__device__ __forceinline__ f32x16 zero16() {
  f32x16 z;
  #pragma unroll
  for (int i = 0; i < 16; ++i) z[i] = 0.0f;
  return z;
}
__device__ __forceinline__ bf16x8 ldA(const unsigned short* __restrict__ wsb, int tile, int l31, int hi, int h) {
  return *(const bf16x8*)(wsb + ((tile * 32 + l31) << 5) + h * 16 + hi * 8);
}

// C layout (32x32x16): col p = lane&31, row j = (reg&3)+8*(reg>>2)+4*hi.
// Next-layer B frags via 4x v_permlane32_swap_b32 (verified R1-R3 network).
__device__ __forceinline__ void transition(const f32x16& acc, bf16x8& b0, bf16x8& b1) {
  unsigned int P[8];
  #pragma unroll
  for (int t = 0; t < 8; ++t)
    P[t] = cvtpk(silu_f(acc[2*t]), silu_f(acc[2*t+1]));
  asm volatile("v_permlane32_swap_b32 %0, %1" : "+v"(P[0]), "+v"(P[2]));
  asm volatile("v_permlane32_swap_b32 %0, %1" : "+v"(P[1]), "+v"(P[3]));
  asm volatile("v_permlane32_swap_b32 %0, %1" : "+v"(P[4]), "+v"(P[6]));
  asm volatile("v_permlane32_swap_b32 %0, %1" : "+v"(P[5]), "+v"(P[7]));
  FragU f0, f1;
  f0.u[0] = P[0]; f0.u[1] = P[1]; f0.u[2] = P[2]; f0.u[3] = P[3];
  f1.u[0] = P[4]; f1.u[1] = P[5]; f1.u[2] = P[6]; f1.u[3] = P[7];
  b0 = f0.v; b1 = f1.v;
}

// R3-verbatim phase: re-zero s_in, stage this l's slice (R3 indexing), compute
// (R3 body). ONLY delta: store goes to natural-72-stride s_out at column OFF.
template<int NL, int OFF, int TB, int SI>
__device__ __forceinline__ void phase(const float* __restrict__ rad,
    const unsigned short* __restrict__ wsb,
    unsigned short* s_in, unsigned short* s_out, const unsigned short* s_pos,
    const int* s_cnt, const int* s_off, const int* s_gpre,
    int base, int vb, int tid)
{
  constexpr int QPR = NL / 4;
  __syncthreads();                       // prev phase done with s_in
  {                                      // zero full s_in region (16 KB)
    int4 z = make_int4(0, 0, 0, 0);
    #pragma unroll
    for (int i = 0; i < (ROWS * 32) / (8 * 256); ++i)
      ((int4*)s_in)[i * 256 + tid] = z;
  }
  __syncthreads();
  // stage-in: coalesced global read of this l's slice, permuted LDS write
  for (int j = tid; j < vb * QPR; j += 256) {
    int i = j / QPR, q = j - i * QPR;
    float4 g = *(const float4*)(rad + (long)(base + i) * 72 + OFF + q * 4);
    int dst = s_pos[i];
    *(uint2*)(s_in + dst * SI + q * 4) = make_uint2(cvtpk(g.x, g.y), cvtpk(g.z, g.w));
  }
  __syncthreads();

  // compute: species-uniform 32-row groups (R3 verbatim)
  const int lane = tid & 63, wid = tid >> 6;
  const int l31 = lane & 31, hi = lane >> 5;
  const int Gtot = s_gpre[4];
  for (int g = wid; g < Gtot; g += 4) {
    int s = (g >= s_gpre[1]) + (g >= s_gpre[2]) + (g >= s_gpre[3]);
    int gi = g - s_gpre[s];
    int goff = s_off[s] + gi * 32;
    int gcnt = s_cnt[s] - gi * 32; if (gcnt > 32) gcnt = 32;
    int li = l31 < gcnt ? l31 : gcnt - 1;
    int row = goff + li;

    FragU bx0, bx1;
    bx0.v = *(const bf16x8*)(s_in + row * SI + hi * 8);
    if (NL > 16) bx1.v = *(const bf16x8*)(s_in + row * SI + 16 + hi * 8);

    f32x16 acc = zero16();
    acc = __builtin_amdgcn_mfma_f32_32x32x16_bf16(ldA(wsb, TB + s, l31, hi, 0), bx0.v, acc, 0, 0, 0);
    if (NL > 16)
      acc = __builtin_amdgcn_mfma_f32_32x32x16_bf16(ldA(wsb, TB + s, l31, hi, 1), bx1.v, acc, 0, 0, 0);
    bf16x8 b0, b1;
    transition(acc, b0, b1);
    acc = zero16();
    acc = __builtin_amdgcn_mfma_f32_32x32x16_bf16(ldA(wsb, TB + 4 + s, l31, hi, 0), b0, acc, 0, 0, 0);
    acc = __builtin_amdgcn_mfma_f32_32x32x16_bf16(ldA(wsb, TB + 4 + s, l31, hi, 1), b1, acc, 0, 0, 0);
    transition(acc, b0, b1);
    acc = zero16();
    acc = __builtin_amdgcn_mfma_f32_32x32x16_bf16(ldA(wsb, TB + 8 + s, l31, hi, 0), b0, acc, 0, 0, 0);
    acc = __builtin_amdgcn_mfma_f32_32x32x16_bf16(ldA(wsb, TB + 8 + s, l31, hi, 1), b1, acc, 0, 0, 0);
    transition(acc, b0, b1);
    acc = zero16();
    acc = __builtin_amdgcn_mfma_f32_32x32x16_bf16(ldA(wsb, TB + 12 + s, l31, hi, 0), b0, acc, 0, 0, 0);
    acc = __builtin_amdgcn_mfma_f32_32x32x16_bf16(ldA(wsb, TB + 12 + s, l31, hi, 1), b1, acc, 0, 0, 0);

    // store: reg quad t -> jo = 8t + 4hi + 0..3 ; natural 72-stride s_out
    if (l31 < gcnt) {
      int obase = (goff + l31) * 72 + OFF;
      #pragma unroll
      for (int t = 0; t < 4; ++t) {
        if (8 * t + 4 * hi + 4 <= NL) {
          *(uint2*)(s_out + obase + 8 * t + 4 * hi) =
              make_uint2(cvtpk(acc[4*t], acc[4*t+1]), cvtpk(acc[4*t+2], acc[4*t+3]));
        }
      }
    }
  }
}

// weights -> bf16 fragment-ready layout in d_ws:
// ws[l][tile 0..15][j 0..31][k 0..31], tile = layer*4 + species, zeros in K/J pads
__global__ void convert_weights_kernel(Wptrs wp, unsigned short* __restrict__ wsb) {
  int idx = blockIdx.x * 256 + threadIdx.x;          // 65536 total
  const int NLs[4] = {24, 20, 16, 12};
  int l = idx >> 14, r = idx & 16383;
  int tile = r >> 10, j = (r >> 5) & 31, k = r & 31;
  int s = tile & 3, layer = tile >> 2;
  int NL = NLs[l];
  const float* w = wp.p[l * 4 + layer];
  float v = 0.0f;
  if (layer == 0)      { if (k < NL) v = w[(s * NL + k) * 32 + j]; }
  else if (layer == 3) { if (j < NL) v = w[(s * 32 + k) * NL + j]; }
  else                 { v = w[(s * 32 + k) * 32 + j]; }
  wsb[idx] = (unsigned short)bfb(v);
}

__global__ __launch_bounds__(256, 3) void RadialBasis_51316269253437_kernel(
    const float* __restrict__ rad, const int* __restrict__ spc,
    const unsigned short* __restrict__ wsb, float* __restrict__ out, int npairs)
{
  __shared__ unsigned short s_in[ROWS * 32];    // 16 KB, re-staged per phase
  __shared__ unsigned short s_out[ROWS * 72];   // 36 KB, natural row layout
  __shared__ unsigned short s_pos[ROWS];
  __shared__ int s_cnt[4], s_fill[4], s_off[4], s_gpre[5];
  const int tid = threadIdx.x;
  const int base = blockIdx.x * ROWS;
  int vb = npairs - base; if (vb > ROWS) vb = ROWS;

  if (tid < 4) { s_cnt[tid] = 0; s_fill[tid] = 0; }
  __syncthreads();
  int sp = -1;
  if (tid < vb) sp = spc[base + tid];
  if (sp >= 0) atomicAdd(&s_cnt[sp], 1);
  __syncthreads();
  if (tid == 0) {
    int o = 0, gp = 0;
    #pragma unroll
    for (int s4 = 0; s4 < 4; ++s4) {
      s_off[s4] = o; o += s_cnt[s4];
      s_gpre[s4] = gp; gp += (s_cnt[s4] + 31) >> 5;
    }
    s_gpre[4] = gp;
  }
  __syncthreads();
  if (sp >= 0) {
    int pos = s_off[sp] + atomicAdd(&s_fill[sp], 1);
    s_pos[tid] = (unsigned short)pos;
  }
  // each phase begins with __syncthreads()
  phase<24,  0,  0, 32>(rad, wsb, s_in, s_out, s_pos, s_cnt, s_off, s_gpre, base, vb, tid);
  phase<20, 24, 16, 32>(rad, wsb, s_in, s_out, s_pos, s_cnt, s_off, s_gpre, base, vb, tid);
  phase<16, 44, 32, 24>(rad, wsb, s_in, s_out, s_pos, s_cnt, s_off, s_gpre, base, vb, tid);
  phase<12, 60, 48, 24>(rad, wsb, s_in, s_out, s_pos, s_cnt, s_off, s_gpre, base, vb, tid);
  __syncthreads();

  // single stage-out: permuted LDS read (natural 72-col rows) -> coalesced float4 writes
  for (int j = tid; j < vb * 18; j += 256) {
    int i = j / 18, q = j - i * 18;
    uint2 w = *(const uint2*)(s_out + (int)s_pos[i] * 72 + q * 4);
    float4 v = make_float4(bf2f((unsigned short)(w.x & 0xffff)),
                           bf2f((unsigned short)(w.x >> 16)),
                           bf2f((unsigned short)(w.y & 0xffff)),
                           bf2f((unsigned short)(w.y >> 16)));
    *(float4*)(out + (long)(base + i) * 72 + q * 4) = v;
  }
}

extern "C" void kernel_launch(void* const* d_in, const int* in_sizes, int n_in,
                              void* d_out, int out_size, void* d_ws, size_t ws_size,
                              hipStream_t stream) {
  const float* rad = (const float*)d_in[0];
  const int* spc = (const int*)d_in[1];
  Wptrs wp;
  for (int i = 0; i < 16; ++i) wp.p[i] = (const float*)d_in[2 + i];
  float* out = (float*)d_out;
  unsigned short* wsb = (unsigned short*)d_ws;
  int npairs = in_sizes[0] / 72;

  convert_weights_kernel<<<dim3(256), dim3(256), 0, stream>>>(wp, wsb);
  int grid = (npairs + ROWS - 1) / ROWS;
  RadialBasis_51316269253437_kernel<<<dim3(grid), dim3(256), 0, stream>>>(rad, spc, wsb, out, npairs);
}

// Round 8
// 361.755 us; speedup vs baseline: 1.5365x; 1.3086x over previous
//
#include <hip/hip_runtime.h>

typedef __attribute__((ext_vector_type(8))) short bf16x8;
typedef __attribute__((ext_vector_type(16))) float f32x16;

union FragU { bf16x8 v; unsigned int u[4]; };
struct Wptrs { const float* p[16]; };

#define ROWS 256
#define THREADS 512

__device__ __forceinline__ unsigned int bfb(float f) {
  unsigned int u = __builtin_bit_cast(unsigned int, f);
  return (u + 0x7fffu + ((u >> 16) & 1u)) >> 16;   // RNE f32 -> bf16 bits
}
__device__ __forceinline__ unsigned int cvtpk(float lo, float hi) {
  unsigned int d;
  asm("v_cvt_pk_bf16_f32 %0, %1, %2" : "=v"(d) : "v"(lo), "v"(hi));
  return d;
}
__device__ __forceinline__ float bf2f(unsigned short b) {
  return __builtin_bit_cast(float, (unsigned int)b << 16);
}
__device__ __forceinline__ float silu_f(float x) {
  float e = __builtin_amdgcn_exp2f(-1.4426950408889634f * x);
  return x * __builtin_amdgcn_rcpf(1.0f + e);
}
__device__ __forceinline__ f32x16 zero16() {
  f32x16 z;
  #pragma unroll
  for (int i = 0; i < 16; ++i) z[i] = 0.0f;
  return z;
}
__device__ __forceinline__ bf16x8 ldA(const unsigned short* __restrict__ wsb, int tile, int l31, int hi, int h) {
  return *(const bf16x8*)(wsb + ((tile * 32 + l31) << 5) + h * 16 + hi * 8);
}

// C layout (32x32x16): col p = lane&31, row j = (reg&3)+8*(reg>>2)+4*hi.
// Next-layer B frags via 4x v_permlane32_swap_b32 (verified R1-R3/R7 network).
__device__ __forceinline__ void transition(const f32x16& acc, bf16x8& b0, bf16x8& b1) {
  unsigned int P[8];
  #pragma unroll
  for (int t = 0; t < 8; ++t)
    P[t] = cvtpk(silu_f(acc[2*t]), silu_f(acc[2*t+1]));
  asm volatile("v_permlane32_swap_b32 %0, %1" : "+v"(P[0]), "+v"(P[2]));
  asm volatile("v_permlane32_swap_b32 %0, %1" : "+v"(P[1]), "+v"(P[3]));
  asm volatile("v_permlane32_swap_b32 %0, %1" : "+v"(P[4]), "+v"(P[6]));
  asm volatile("v_permlane32_swap_b32 %0, %1" : "+v"(P[5]), "+v"(P[7]));
  FragU f0, f1;
  f0.u[0] = P[0]; f0.u[1] = P[1]; f0.u[2] = P[2]; f0.u[3] = P[3];
  f1.u[0] = P[4]; f1.u[1] = P[5]; f1.u[2] = P[6]; f1.u[3] = P[7];
  b0 = f0.v; b1 = f1.v;
}

// R7-verbatim phase (only thread-count strides changed): re-zero s_in, stage
// this l's slice, compute, store to natural-72-stride s_out at column OFF.
template<int NL, int OFF, int TB, int SI>
__device__ __forceinline__ void phase(const float* __restrict__ rad,
    const unsigned short* __restrict__ wsb,
    unsigned short* s_in, unsigned short* s_out, const unsigned short* s_pos,
    const int* s_cnt, const int* s_off, const int* s_gpre,
    int base, int vb, int tid)
{
  constexpr int QPR = NL / 4;
  __syncthreads();                       // prev phase done with s_in
  {                                      // zero full s_in region (16 KB)
    int4 z = make_int4(0, 0, 0, 0);
    #pragma unroll
    for (int i = 0; i < (ROWS * 32) / (8 * THREADS); ++i)
      ((int4*)s_in)[i * THREADS + tid] = z;
  }
  __syncthreads();
  // stage-in: coalesced global read of this l's slice, permuted LDS write
  for (int j = tid; j < vb * QPR; j += THREADS) {
    int i = j / QPR, q = j - i * QPR;
    float4 g = *(const float4*)(rad + (long)(base + i) * 72 + OFF + q * 4);
    int dst = s_pos[i];
    *(uint2*)(s_in + dst * SI + q * 4) = make_uint2(cvtpk(g.x, g.y), cvtpk(g.z, g.w));
  }
  __syncthreads();

  // compute: species-uniform 32-row groups (R7 verbatim)
  const int lane = tid & 63, wid = tid >> 6;
  const int l31 = lane & 31, hi = lane >> 5;
  const int Gtot = s_gpre[4];
  for (int g = wid; g < Gtot; g += THREADS / 64) {
    int s = (g >= s_gpre[1]) + (g >= s_gpre[2]) + (g >= s_gpre[3]);
    int gi = g - s_gpre[s];
    int goff = s_off[s] + gi * 32;
    int gcnt = s_cnt[s] - gi * 32; if (gcnt > 32) gcnt = 32;
    int li = l31 < gcnt ? l31 : gcnt - 1;
    int row = goff + li;

    FragU bx0, bx1;
    bx0.v = *(const bf16x8*)(s_in + row * SI + hi * 8);
    if (NL > 16) bx1.v = *(const bf16x8*)(s_in + row * SI + 16 + hi * 8);

    f32x16 acc = zero16();
    acc = __builtin_amdgcn_mfma_f32_32x32x16_bf16(ldA(wsb, TB + s, l31, hi, 0), bx0.v, acc, 0, 0, 0);
    if (NL > 16)
      acc = __builtin_amdgcn_mfma_f32_32x32x16_bf16(ldA(wsb, TB + s, l31, hi, 1), bx1.v, acc, 0, 0, 0);
    bf16x8 b0, b1;
    transition(acc, b0, b1);
    acc = zero16();
    acc = __builtin_amdgcn_mfma_f32_32x32x16_bf16(ldA(wsb, TB + 4 + s, l31, hi, 0), b0, acc, 0, 0, 0);
    acc = __builtin_amdgcn_mfma_f32_32x32x16_bf16(ldA(wsb, TB + 4 + s, l31, hi, 1), b1, acc, 0, 0, 0);
    transition(acc, b0, b1);
    acc = zero16();
    acc = __builtin_amdgcn_mfma_f32_32x32x16_bf16(ldA(wsb, TB + 8 + s, l31, hi, 0), b0, acc, 0, 0, 0);
    acc = __builtin_amdgcn_mfma_f32_32x32x16_bf16(ldA(wsb, TB + 8 + s, l31, hi, 1), b1, acc, 0, 0, 0);
    transition(acc, b0, b1);
    acc = zero16();
    acc = __builtin_amdgcn_mfma_f32_32x32x16_bf16(ldA(wsb, TB + 12 + s, l31, hi, 0), b0, acc, 0, 0, 0);
    acc = __builtin_amdgcn_mfma_f32_32x32x16_bf16(ldA(wsb, TB + 12 + s, l31, hi, 1), b1, acc, 0, 0, 0);

    // store: reg quad t -> jo = 8t + 4hi + 0..3 ; natural 72-stride s_out
    if (l31 < gcnt) {
      int obase = (goff + l31) * 72 + OFF;
      #pragma unroll
      for (int t = 0; t < 4; ++t) {
        if (8 * t + 4 * hi + 4 <= NL) {
          *(uint2*)(s_out + obase + 8 * t + 4 * hi) =
              make_uint2(cvtpk(acc[4*t], acc[4*t+1]), cvtpk(acc[4*t+2], acc[4*t+3]));
        }
      }
    }
  }
}

// weights -> bf16 fragment-ready layout in d_ws:
// ws[l][tile 0..15][j 0..31][k 0..31], tile = layer*4 + species, zeros in K/J pads
__global__ void convert_weights_kernel(Wptrs wp, unsigned short* __restrict__ wsb) {
  int idx = blockIdx.x * 256 + threadIdx.x;          // 65536 total
  const int NLs[4] = {24, 20, 16, 12};
  int l = idx >> 14, r = idx & 16383;
  int tile = r >> 10, j = (r >> 5) & 31, k = r & 31;
  int s = tile & 3, layer = tile >> 2;
  int NL = NLs[l];
  const float* w = wp.p[l * 4 + layer];
  float v = 0.0f;
  if (layer == 0)      { if (k < NL) v = w[(s * NL + k) * 32 + j]; }
  else if (layer == 3) { if (j < NL) v = w[(s * 32 + k) * NL + j]; }
  else                 { v = w[(s * 32 + k) * 32 + j]; }
  wsb[idx] = (unsigned short)bfb(v);
}

__global__ __launch_bounds__(THREADS, 6) void RadialBasis_51316269253437_kernel(
    const float* __restrict__ rad, const int* __restrict__ spc,
    const unsigned short* __restrict__ wsb, float* __restrict__ out, int npairs)
{
  __shared__ unsigned short s_in[ROWS * 32];    // 16 KB, re-staged per phase
  __shared__ unsigned short s_out[ROWS * 72];   // 36 KB, natural row layout
  __shared__ unsigned short s_pos[ROWS];
  __shared__ int s_cnt[4], s_fill[4], s_off[4], s_gpre[5];
  const int tid = threadIdx.x;
  const int base = blockIdx.x * ROWS;
  int vb = npairs - base; if (vb > ROWS) vb = ROWS;

  if (tid < 4) { s_cnt[tid] = 0; s_fill[tid] = 0; }
  __syncthreads();
  int sp = -1;
  if (tid < vb) sp = spc[base + tid];
  if (sp >= 0) atomicAdd(&s_cnt[sp], 1);
  __syncthreads();
  if (tid == 0) {
    int o = 0, gp = 0;
    #pragma unroll
    for (int s4 = 0; s4 < 4; ++s4) {
      s_off[s4] = o; o += s_cnt[s4];
      s_gpre[s4] = gp; gp += (s_cnt[s4] + 31) >> 5;
    }
    s_gpre[4] = gp;
  }
  __syncthreads();
  if (sp >= 0) {
    int pos = s_off[sp] + atomicAdd(&s_fill[sp], 1);
    s_pos[tid] = (unsigned short)pos;
  }
  // each phase begins with __syncthreads()
  phase<24,  0,  0, 32>(rad, wsb, s_in, s_out, s_pos, s_cnt, s_off, s_gpre, base, vb, tid);
  phase<20, 24, 16, 32>(rad, wsb, s_in, s_out, s_pos, s_cnt, s_off, s_gpre, base, vb, tid);
  phase<16, 44, 32, 24>(rad, wsb, s_in, s_out, s_pos, s_cnt, s_off, s_gpre, base, vb, tid);
  phase<12, 60, 48, 24>(rad, wsb, s_in, s_out, s_pos, s_cnt, s_off, s_gpre, base, vb, tid);
  __syncthreads();

  // single stage-out: permuted LDS read (natural 72-col rows) -> coalesced float4 writes
  for (int j = tid; j < vb * 18; j += THREADS) {
    int i = j / 18, q = j - i * 18;
    uint2 w = *(const uint2*)(s_out + (int)s_pos[i] * 72 + q * 4);
    float4 v = make_float4(bf2f((unsigned short)(w.x & 0xffff)),
                           bf2f((unsigned short)(w.x >> 16)),
                           bf2f((unsigned short)(w.y & 0xffff)),
                           bf2f((unsigned short)(w.y >> 16)));
    *(float4*)(out + (long)(base + i) * 72 + q * 4) = v;
  }
}

extern "C" void kernel_launch(void* const* d_in, const int* in_sizes, int n_in,
                              void* d_out, int out_size, void* d_ws, size_t ws_size,
                              hipStream_t stream) {
  const float* rad = (const float*)d_in[0];
  const int* spc = (const int*)d_in[1];
  Wptrs wp;
  for (int i = 0; i < 16; ++i) wp.p[i] = (const float*)d_in[2 + i];
  float* out = (float*)d_out;
  unsigned short* wsb = (unsigned short*)d_ws;
  int npairs = in_sizes[0] / 72;

  convert_weights_kernel<<<dim3(256), dim3(256), 0, stream>>>(wp, wsb);
  int grid = (npairs + ROWS - 1) / ROWS;
  RadialBasis_51316269253437_kernel<<<dim3(grid), dim3(THREADS), 0, stream>>>(rad, spc, wsb, out, npairs);
}